// Round 1
// 257.948 us; speedup vs baseline: 1.0147x; 1.0147x over previous
//
#include <hip/hip_runtime.h>
#include <math.h>

#define C 4096

typedef float f4 __attribute__((ext_vector_type(4)));

// ---------------------------------------------------------------------------
// Kernel 1: fused token-shift mix + three matvecs (kw@xk, vw@xv, rw@xr).
// Grid: 3072 blocks of 256. Block b: matrix m = b>>10, rows (b&1023)*4 .. +3,
// one wave per row. The mixed x-vector is computed inline and staged in LDS.
//
// Each wave loads its whole 16 KiB row into registers (16 dwordx4 loads in
// flight). The sched_barrier(0) after the load loop is load-bearing: without
// it the compiler interleaves loads with FMAs to save registers (previous
// build: VGPR_Count=32 => ~2-4 loads in flight => 2.8 TB/s cap). With it the
// full 16-deep issue is preserved (VGPR ~90), maximizing per-wave MLP.
// ---------------------------------------------------------------------------
__global__ __launch_bounds__(256) void matvec3_kernel(
    const float* __restrict__ kw, const float* __restrict__ vw, const float* __restrict__ rw,
    const float* __restrict__ x, const float* __restrict__ state,
    const float* __restrict__ tmk, const float* __restrict__ tmv, const float* __restrict__ tmr,
    float* __restrict__ kk, float* __restrict__ vvo, float* __restrict__ rr) {
    __shared__ f4 xs[C / 4];   // 16 KiB: mixed input vector

    const int t = threadIdx.x;
    const int m = blockIdx.x >> 10;

    const float* W;
    const float* tm;
    float* out;
    if (m == 0)      { W = kw; tm = tmk; out = kk;  }
    else if (m == 1) { W = vw; tm = tmv; out = vvo; }
    else             { W = rw; tm = tmr; out = rr;  }

    // Stage mixed vector: xm = x*tm + state*(1-tm)
    const f4* x4 = (const f4*)x;
    const f4* s4 = (const f4*)state;
    const f4* t4 = (const f4*)tm;
#pragma unroll
    for (int j = 0; j < 4; ++j) {
        int i = j * 256 + t;
        f4 xi = x4[i], si = s4[i], ti = t4[i];
        f4 r;
        r.x = xi.x * ti.x + si.x * (1.0f - ti.x);
        r.y = xi.y * ti.y + si.y * (1.0f - ti.y);
        r.z = xi.z * ti.z + si.z * (1.0f - ti.z);
        r.w = xi.w * ti.w + si.w * (1.0f - ti.w);
        xs[i] = r;
    }
    __syncthreads();

    const int wave = t >> 6;
    const int lane = t & 63;
    const int row  = (blockIdx.x & 1023) * 4 + wave;
    const f4* Wrow = (const f4*)(W + (size_t)row * C);

    // Issue the entire row's loads up front (16 independent dwordx4 loads).
    f4 wreg[16];
#pragma unroll
    for (int it = 0; it < 16; ++it) wreg[it] = Wrow[it * 64 + lane];
    // Do NOT let the scheduler sink loads into the consume loop.
    __builtin_amdgcn_sched_barrier(0);

    // Consume against LDS copies of x, 4 independent accumulator chains.
    float s0 = 0.f, s1 = 0.f, s2 = 0.f, s3 = 0.f;
#pragma unroll
    for (int it = 0; it < 16; ++it) {
        f4 xx = xs[it * 64 + lane];
        f4 w  = wreg[it];
        s0 += w.x * xx.x;
        s1 += w.y * xx.y;
        s2 += w.z * xx.z;
        s3 += w.w * xx.w;
    }
    float sum = (s0 + s1) + (s2 + s3);
#pragma unroll
    for (int off = 32; off > 0; off >>= 1) sum += __shfl_down(sum, off, 64);
    if (lane == 0) out[row] = sum;
}

// ---------------------------------------------------------------------------
// Kernel 2: WKV elementwise core + state updates + new_state = x
// ---------------------------------------------------------------------------
__global__ void wkv_kernel(const float* __restrict__ kk, const float* __restrict__ vv,
                           const float* __restrict__ rr,
                           const float* __restrict__ aa, const float* __restrict__ bb,
                           const float* __restrict__ pp,
                           const float* __restrict__ time_first,
                           const float* __restrict__ time_decay,
                           const float* __restrict__ x,
                           float* __restrict__ rwkv,
                           float* __restrict__ new_state,
                           float* __restrict__ out_sa, float* __restrict__ out_sb,
                           float* __restrict__ out_sp) {
    int i = blockIdx.x * blockDim.x + threadIdx.x;
    if (i < C) {
        float k = kk[i], v = vv[i];
        float a_ = aa[i], b_ = bb[i], p_ = pp[i];

        float ww = time_first[i] + k;
        float p  = fmaxf(p_, ww);
        float e1 = expf(p_ - p);
        float e2 = expf(ww - p);
        float a  = e1 * a_ + e2 * v;
        float b  = e1 * b_ + e2;

        float ww2 = p_ + time_decay[i];
        float p2  = fmaxf(ww2, k);
        float e1b = expf(ww2 - p2);
        float e2b = expf(k - p2);
        out_sa[i] = e1b * a_ + e2b * v;
        out_sb[i] = e1b * b_ + e2b;
        out_sp[i] = p2;

        new_state[i] = x[i];

        float r = 1.0f / (1.0f + expf(-rr[i]));
        rwkv[i] = r * (a / b);
    }
}

// ---------------------------------------------------------------------------
// Kernel 3: final matvec ow @ (r*wkv) -> out. Same GEMV core, rwkv via LDS.
// ow weights are loaded NONTEMPORAL: ow has zero reuse and the 4-matrix
// working set (268 MB) just exceeds the 256 MiB L3 -> cyclic thrash. Keeping
// ow out of L3 leaves kw/vw/rw resident for the next iteration's matvec3.
// ---------------------------------------------------------------------------
__global__ __launch_bounds__(256) void matvec_kernel(const float* __restrict__ W,
                                                     const float* __restrict__ xin,
                                                     float* __restrict__ out) {
    __shared__ f4 xs[C / 4];
    const int t = threadIdx.x;

    const f4* x4 = (const f4*)xin;
#pragma unroll
    for (int j = 0; j < 4; ++j) {
        int i = j * 256 + t;
        xs[i] = x4[i];
    }
    __syncthreads();

    const int wave = t >> 6;
    const int lane = t & 63;
    const int row  = blockIdx.x * 4 + wave;
    const f4* Wrow = (const f4*)(W + (size_t)row * C);

    f4 wreg[16];
#pragma unroll
    for (int it = 0; it < 16; ++it)
        wreg[it] = __builtin_nontemporal_load(&Wrow[it * 64 + lane]);
    __builtin_amdgcn_sched_barrier(0);

    float s0 = 0.f, s1 = 0.f, s2 = 0.f, s3 = 0.f;
#pragma unroll
    for (int it = 0; it < 16; ++it) {
        f4 xx = xs[it * 64 + lane];
        f4 w  = wreg[it];
        s0 += w.x * xx.x;
        s1 += w.y * xx.y;
        s2 += w.z * xx.z;
        s3 += w.w * xx.w;
    }
    float sum = (s0 + s1) + (s2 + s3);
#pragma unroll
    for (int off = 32; off > 0; off >>= 1) sum += __shfl_down(sum, off, 64);
    if (lane == 0) out[row] = sum;
}

// ---------------------------------------------------------------------------
extern "C" void kernel_launch(void* const* d_in, const int* in_sizes, int n_in,
                              void* d_out, int out_size, void* d_ws, size_t ws_size,
                              hipStream_t stream) {
    const float* x          = (const float*)d_in[0];
    const float* state      = (const float*)d_in[1];
    const float* state_a    = (const float*)d_in[2];
    const float* state_b    = (const float*)d_in[3];
    const float* state_p    = (const float*)d_in[4];
    const float* tmk        = (const float*)d_in[5];
    const float* tmv        = (const float*)d_in[6];
    const float* tmr        = (const float*)d_in[7];
    const float* time_first = (const float*)d_in[8];
    const float* time_decay = (const float*)d_in[9];
    const float* kw         = (const float*)d_in[10];
    const float* vw         = (const float*)d_in[11];
    const float* rw         = (const float*)d_in[12];
    const float* ow         = (const float*)d_in[13];

    float* out       = (float*)d_out;        // [0:C)     out
    float* new_state = out + C;              // [C:2C)    new_state = x
    float* new_sa    = out + 2 * C;          // [2C:3C)   new_state_a
    float* new_sb    = out + 3 * C;          // [3C:4C)   new_state_b
    float* new_sp    = out + 4 * C;          // [4C:5C)   new_state_p

    float* ws   = (float*)d_ws;
    float* kk   = ws;
    float* vv   = ws + C;
    float* rr   = ws + 2 * C;
    float* rwkv = ws + 3 * C;

    matvec3_kernel<<<3 * C / 4, 256, 0, stream>>>(kw, vw, rw, x, state, tmk, tmv, tmr,
                                                  kk, vv, rr);

    wkv_kernel<<<C / 256, 256, 0, stream>>>(kk, vv, rr, state_a, state_b, state_p,
                                            time_first, time_decay, x,
                                            rwkv, new_state, new_sa, new_sb, new_sp);

    matvec_kernel<<<C / 4, 256, 0, stream>>>(ow, rwkv, out);
}